// Round 3
// baseline (307.514 us; speedup 1.0000x reference)
//
#include <hip/hip_runtime.h>

#define N_ 4
#define C_ 256
#define H_ 128
#define W_ 128
#define HW_ (H_*W_)
#define OC 9
#define EPS_ 1e-5f
#define NBLK 256           // grid size; co-residency proof in header comment
#define PPB 4              // planes per block

typedef float nfloat4 __attribute__((ext_vector_type(4)));

// Grid barrier from device-scope atomics. Safe because all NBLK blocks are
// co-resident under ANY packing: LDS 68.6KB -> <=2 blk/CU, 1024 thr -> <=2,
// VGPR<=128 (launch_bounds) -> >=1 blk/CU; min capacity 256 = grid.
// arrive/wait split lets blocks do useful work while the grid catches up.
__device__ __forceinline__ void gbar_arrive(unsigned* cnt) {
    __syncthreads();                       // all block threads' stores issued
    if (threadIdx.x == 0) {
        __threadfence();                   // agent-scope release (L1/L2 wb)
        __hip_atomic_fetch_add(cnt, 1u, __ATOMIC_RELEASE,
                               __HIP_MEMORY_SCOPE_AGENT);
    }
}
__device__ __forceinline__ void gbar_wait(unsigned* cnt) {
    if (threadIdx.x == 0) {
        int bail = 0;
        while (__hip_atomic_load(cnt, __ATOMIC_ACQUIRE,
                                 __HIP_MEMORY_SCOPE_AGENT) < NBLK) {
            __builtin_amdgcn_s_sleep(8);
            if (++bail > 100000) break;    // ~20ms valve: fail clean, no hang
        }
        __threadfence();                   // agent-scope acquire (L1/L2 inv)
    }
    __syncthreads();
}

// Stage one full 128x128 plane (+1 halo row top/bottom, zero; halo cols at
// lds col 0 and 129, zero) into lds[130][132]. 4160 coalesced float4 loads.
__device__ __forceinline__ void stage_plane(float* lds, const float* xin,
                                            int t, bool halo) {
    if (halo && t < 130) { lds[t * 132] = 0.f; lds[t * 132 + 129] = 0.f; }
    #pragma unroll
    for (int i = 0; i < 5; ++i) {
        int vi = i * 1024 + t;
        if (vi < 4160) {
            int lr = vi >> 5;              // lds row 0..129
            int c4 = (vi & 31) << 2;       // col 0,4,...,124
            int gr = lr - 1;               // global row
            float4 val = make_float4(0.f, 0.f, 0.f, 0.f);
            if (gr >= 0 && gr < H_) val = *(const float4*)&xin[gr * W_ + c4];
            float* d = &lds[lr * 132 + c4 + 1];
            d[0] = val.x; d[1] = val.y; d[2] = val.z; d[3] = val.w;
        }
    }
}

// One plain (non-cooperative) kernel, 256 blocks x 1024 threads.
// Phase 1: each block pools 4 planes (4 groups of 256 threads).
// barrier -> Phase 2: blocks 0..8 fused 1x1conv+BN (others prestage plane 0)
// barrier -> Phase 3: depthwise 3x3, whole-plane LDS tile, 4 planes/block.
__global__ __launch_bounds__(1024, 4) void fused_kernel(
        const float* __restrict__ x, const float* __restrict__ wconv,
        const float* __restrict__ gamma, const float* __restrict__ beta,
        float* __restrict__ xpT, float* __restrict__ w9,
        float* __restrict__ out, unsigned* __restrict__ bar) {
    int b = blockIdx.x;
    int t = threadIdx.x;
    __shared__ __align__(16) float lds[130 * 132];   // 68640 B, phase-reused
    const int pb = b * PPB;

    // ---------------- Phase 1: pool (4 planes, 1 per 256-thread group) ----
    {
        int g = t >> 8, tt = t & 255;      // group = waves 4g..4g+3
        int plane = pb + g;
        int n = plane >> 8, c = plane & 255;
        const float4* xv = (const float4*)(x + (size_t)plane * HW_);
        float* part = lds + (g << 10);
        int w = tt >> 6, l = tt & 63;
        int j = (l & 31) >> 1;             // col bin 0..15
        bool writer = (l < 32) && ((l & 1) == 0);
        #pragma unroll
        for (int k = 0; k < 16; ++k) {
            float4 v = xv[k * 256 + tt];   // coalesced
            float s = v.x + v.y + v.z + v.w;
            s += __shfl_xor(s, 1);         // pair lanes -> 8 cols of one row
            s += __shfl_xor(s, 32);        // combine the wave's two rows
            if (writer) part[w * 256 + k * 16 + j] = s;
        }
        __syncthreads();
        float r = part[tt] + part[256 + tt] + part[512 + tt] + part[768 + tt];
        xpT[((size_t)c << 10) + (n << 8) + tt] = r * (1.f / 64.f);
    }

    gbar_arrive(bar);                      // xpT released device-wide
    if (b >= OC) stage_plane(lds, x + (size_t)pb * HW_, t, true);
    gbar_wait(bar);

    // ---------------- Phase 2: conv+BN on blocks 0..8 ----------------
    if (b < OC) {
        int o = b;
        int q = t & 255, ch = t >> 8;      // sample quad / 64-channel chunk
        const float4* xp4 = (const float4*)xpT;    // [c][256 quads]
        const float* wrow = wconv + (o << 8);
        float ax = 0.f, ay = 0.f, az = 0.f, aw = 0.f;
        int c0 = ch << 6;
        #pragma unroll 16
        for (int c = c0; c < c0 + 64; ++c) {
            float wv = wrow[c];
            float4 v = xp4[(c << 8) + q];
            ax += wv * v.x; ay += wv * v.y; az += wv * v.z; aw += wv * v.w;
        }
        float* red = lds;                  // [3][256][4]
        float* ls  = lds + 3072;           // [32]
        float* sc  = lds + 3104;           // [2]
        if (ch) {
            float* r = red + ((ch - 1) << 10) + (q << 2);
            r[0] = ax; r[1] = ay; r[2] = az; r[3] = aw;
        }
        __syncthreads();
        if (ch == 0) {
            int q4 = q << 2;
            ax += red[q4]     + red[1024 + q4]     + red[2048 + q4];
            ay += red[q4 + 1] + red[1024 + q4 + 1] + red[2048 + q4 + 1];
            az += red[q4 + 2] + red[1024 + q4 + 2] + red[2048 + q4 + 2];
            aw += red[q4 + 3] + red[1024 + q4 + 3] + red[2048 + q4 + 3];
            float sum = ax + ay + az + aw;
            float sq  = ax*ax + ay*ay + az*az + aw*aw;
            #pragma unroll
            for (int off = 32; off > 0; off >>= 1) {
                sum += __shfl_down(sum, off);
                sq  += __shfl_down(sq,  off);
            }
            if ((q & 63) == 0) { ls[q >> 6] = sum; ls[16 + (q >> 6)] = sq; }
        }
        __syncthreads();
        if (t == 0) {
            float S = ls[0] + ls[1] + ls[2] + ls[3];
            float Q = ls[16] + ls[17] + ls[18] + ls[19];
            float mu = S * (1.f / 1024.f);
            float var = Q * (1.f / 1024.f) - mu * mu;
            float scale = gamma[o] * rsqrtf(var + EPS_);
            sc[0] = scale;
            sc[1] = beta[o] - mu * scale;
        }
        __syncthreads();
        if (ch == 0) {
            float scale = sc[0], shift = sc[1];
            int s0 = q << 2;
            w9[(s0 + 0) * 9 + o] = ax * scale + shift;
            w9[(s0 + 1) * 9 + o] = ay * scale + shift;
            w9[(s0 + 2) * 9 + o] = az * scale + shift;
            w9[(s0 + 3) * 9 + o] = aw * scale + shift;
        }
    }

    gbar_arrive(bar + 1);                  // w9 released device-wide
    if (b < OC) stage_plane(lds, x + (size_t)pb * HW_, t, true);
    gbar_wait(bar + 1);

    // ---------------- Phase 3: depthwise 3x3, whole-plane tile ----------
    int mr = t >> 5, mc = t & 31;          // 4x4 micro-tile per thread
    int olr = mr * 4, oc0 = mc * 4;
    #pragma unroll 1
    for (int g = 0; g < PPB; ++g) {
        int plane = pb + g;
        if (g > 0) {
            __syncthreads();               // prior compute done reading lds
            stage_plane(lds, x + (size_t)plane * HW_, t, false);
            __syncthreads();
        }
        const float* wp = w9 + plane * 9;  // block-uniform -> scalar loads
        float w[9];
        #pragma unroll
        for (int i = 0; i < 9; ++i) w[i] = wp[i];
        float* po = out + (size_t)plane * HW_;
        float rowv[6][6];                  // lds rows olr..olr+5 = in rows -1..+4
        #pragma unroll
        for (int j = 0; j < 6; ++j) {
            const float* rp = &lds[(olr + j) * 132 + oc0];
            float4 a = *(const float4*)rp; // 16B-aligned ds_read_b128
            rowv[j][0] = a.x; rowv[j][1] = a.y; rowv[j][2] = a.z; rowv[j][3] = a.w;
            rowv[j][4] = rp[4]; rowv[j][5] = rp[5];
        }
        #pragma unroll
        for (int rr = 0; rr < 4; ++rr) {
            float res[4];
            #pragma unroll
            for (int cc = 0; cc < 4; ++cc) {
                float s = 0.f;
                #pragma unroll
                for (int dy = 0; dy < 3; ++dy)
                    #pragma unroll
                    for (int dx = 0; dx < 3; ++dx)
                        s += w[dy * 3 + dx] * rowv[rr + dy][cc + dx];
                res[cc] = s;
            }
            nfloat4 rv = { res[0], res[1], res[2], res[3] };
            __builtin_nontemporal_store(rv,
                (nfloat4*)&po[(olr + rr) * W_ + oc0]);
        }
    }
}

extern "C" void kernel_launch(void* const* d_in, const int* in_sizes, int n_in,
                              void* d_out, int out_size, void* d_ws, size_t ws_size,
                              hipStream_t stream) {
    const float* x     = (const float*)d_in[0];
    const float* wconv = (const float*)d_in[1];
    const float* gamma = (const float*)d_in[2];
    const float* beta  = (const float*)d_in[3];
    float* out = (float*)d_out;

    float* xpT = (float*)d_ws;                   // C*N*256 = 262144 floats
    float* w9  = xpT + C_ * N_ * 256;            // N*256*OC = 9216 floats
    unsigned* bar = (unsigned*)(w9 + N_ * 256 * OC);   // 2 counters

    hipMemsetAsync(bar, 0, 2 * sizeof(unsigned), stream);  // capture-safe
    hipLaunchKernelGGL(fused_kernel, dim3(NBLK), dim3(1024), 0, stream,
                       x, wconv, gamma, beta, xpT, w9, out, bar);
}

// Round 4
// 147.103 us; speedup vs baseline: 2.0905x; 2.0905x over previous
//
#include <hip/hip_runtime.h>

#define N_ 4
#define C_ 256
#define H_ 128
#define W_ 128
#define HW_ (H_*W_)
#define OC 9
#define EPS_ 1e-5f
#define NBLK 256           // grid; 1 block/CU forced by 84KB LDS -> all resident
#define PPB 4              // planes per block

typedef float nfloat4 __attribute__((ext_vector_type(4)));

// Agent-scope coherent accessors: sc1 ops bypass the non-coherent per-XCD L2
// and complete at the coherence point (L3). NO cache-maintenance instructions
// are generated for RELAXED ordering (the R3 221us stall was buffer_wbl2/
// buffer_inv storms from __threadfence).
#define AST(p, v) __hip_atomic_store((p), (v), __ATOMIC_RELAXED, __HIP_MEMORY_SCOPE_AGENT)
#define ALD(p)    __hip_atomic_load((p), __ATOMIC_RELAXED, __HIP_MEMORY_SCOPE_AGENT)

// Barrier from relaxed atomics only. Safe: all 256 blocks co-resident
// (84KB LDS -> exactly 1 block/CU, 256 CUs). Producer ordering: sc1 data
// stores are drained by the vmcnt(0) the compiler emits at __syncthreads,
// so they are globally visible before the arrive-add issues.
__device__ __forceinline__ void gbar_arrive(unsigned* cnt) {
    __syncthreads();
    asm volatile("" ::: "memory");
    if (threadIdx.x == 0)
        __hip_atomic_fetch_add(cnt, 1u, __ATOMIC_RELAXED,
                               __HIP_MEMORY_SCOPE_AGENT);
}
__device__ __forceinline__ void gbar_wait(unsigned* cnt) {
    if (threadIdx.x == 0) {
        int bail = 0;
        while (__hip_atomic_load(cnt, __ATOMIC_RELAXED,
                                 __HIP_MEMORY_SCOPE_AGENT) < NBLK) {
            __builtin_amdgcn_s_sleep(2);
            if (++bail > 2000000) break;   // valve: fail clean, never hang
        }
    }
    asm volatile("" ::: "memory");
    __syncthreads();
}

// Stage one full 128x128 plane (+zero halo row top/bottom, zero halo cols at
// lds col 0 and 129) into plane_lds[130][132]. 4160 coalesced float4 loads.
__device__ __forceinline__ void stage_plane(float* plane_lds, const float* xin,
                                            int t, bool halo) {
    if (halo && t < 130) { plane_lds[t * 132] = 0.f; plane_lds[t * 132 + 129] = 0.f; }
    #pragma unroll
    for (int i = 0; i < 5; ++i) {
        int vi = i * 1024 + t;
        if (vi < 4160) {
            int lr = vi >> 5;              // lds row 0..129
            int c4 = (vi & 31) << 2;       // col 0,4,...,124
            int gr = lr - 1;               // global row
            float4 val = make_float4(0.f, 0.f, 0.f, 0.f);
            if (gr >= 0 && gr < H_) val = *(const float4*)&xin[gr * W_ + c4];
            float* d = &plane_lds[lr * 132 + c4 + 1];
            d[0] = val.x; d[1] = val.y; d[2] = val.z; d[3] = val.w;
        }
    }
}

// One kernel, 256 blocks x 1024 threads, 1 block/CU.
// P1: pool 4 planes -> xpT (sc1 stores).  bar0
// prestage plane 0 to LDS; blocks 0..8: conv+BN -> w9 (sc1).  bar1
// P3: dwconv 4 planes, reg-pipelined staging, nt stores.
__global__ __launch_bounds__(1024) void fused_kernel(
        const float* __restrict__ x, const float* __restrict__ wconv,
        const float* __restrict__ gamma, const float* __restrict__ beta,
        float* __restrict__ xpT, float* __restrict__ w9,
        float* __restrict__ out, unsigned* __restrict__ bar) {
    int b = blockIdx.x;
    int t = threadIdx.x;
    // 84000B static LDS: plane buffer 17160 + scratch 34 + pad -> 1 block/CU
    __shared__ __align__(16) float lds[21000];
    float* plane_lds = lds;            // [130][132]
    float* ls = lds + 17160;           // [32] BN partials
    float* sc = lds + 17192;           // [2]  BN scale/shift
    const int pb = b * PPB;

    // ---------------- Phase 1: pool (4 planes, 1 per 256-thread group) ----
    {
        int g = t >> 8, tt = t & 255;
        int plane = pb + g;
        int n = plane >> 8, c = plane & 255;
        const float4* xv = (const float4*)(x + (size_t)plane * HW_);
        float* part = lds + (g << 10);
        int w = tt >> 6, l = tt & 63;
        int j = (l & 31) >> 1;             // col bin 0..15
        bool writer = (l < 32) && ((l & 1) == 0);
        #pragma unroll
        for (int k = 0; k < 16; ++k) {
            float4 v = xv[k * 256 + tt];   // coalesced
            float s = v.x + v.y + v.z + v.w;
            s += __shfl_xor(s, 1);
            s += __shfl_xor(s, 32);
            if (writer) part[w * 256 + k * 16 + j] = s;
        }
        __syncthreads();
        float r = part[tt] + part[256 + tt] + part[512 + tt] + part[768 + tt];
        AST(&xpT[((size_t)c << 10) + (n << 8) + tt], r * (1.f / 64.f));
    }

    gbar_arrive(bar);                      // syncthreads drains sc1 stores

    // prestage plane 0 (all blocks; overlaps bar0 skew + phase 2)
    stage_plane(plane_lds, x + (size_t)pb * HW_, t, true);

    // ---------------- Phase 2: conv+BN on blocks 0..8 ----------------
    if (b < OC) {
        gbar_wait(bar);                    // xpT visible (all at L3)
        int o = b;
        const float* wrow = wconv + (o << 8);
        float acc = 0.f;
        #pragma unroll 16
        for (int c = 0; c < 256; ++c)
            acc += wrow[c] * ALD(&xpT[(c << 10) + t]);   // coalesced sc1 loads
        float sum = acc, sq = acc * acc;
        #pragma unroll
        for (int off = 32; off > 0; off >>= 1) {
            sum += __shfl_down(sum, off);
            sq  += __shfl_down(sq,  off);
        }
        int w = t >> 6;
        if ((t & 63) == 0) { ls[w] = sum; ls[16 + w] = sq; }
        __syncthreads();
        if (t == 0) {
            float S = 0.f, Q = 0.f;
            #pragma unroll
            for (int i = 0; i < 16; ++i) { S += ls[i]; Q += ls[16 + i]; }
            float mu = S * (1.f / 1024.f);
            float var = Q * (1.f / 1024.f) - mu * mu;
            float scale = gamma[o] * rsqrtf(var + EPS_);
            sc[0] = scale;
            sc[1] = beta[o] - mu * scale;
        }
        __syncthreads();
        AST(&w9[t * 9 + o], acc * sc[0] + sc[1]);
    }

    gbar_arrive(bar + 1);                  // drains w9 sc1 stores (b<9)

    // issue plane-1 global loads now: in flight during bar1 spin
    float4 pre[5];
    {
        const float* xn = x + (size_t)(pb + 1) * HW_;
        #pragma unroll
        for (int i = 0; i < 5; ++i) {
            int vi = i * 1024 + t;
            if (vi < 4160) {
                int lr = vi >> 5, c4 = (vi & 31) << 2, gr = lr - 1;
                pre[i] = (gr >= 0 && gr < H_)
                       ? *(const float4*)&xn[gr * W_ + c4]
                       : make_float4(0.f, 0.f, 0.f, 0.f);
            }
        }
    }

    gbar_wait(bar + 1);                    // w9 visible

    // ---------------- Phase 3: depthwise 3x3, whole-plane LDS tile -------
    int mr = t >> 5, mc = t & 31;          // 4x4 micro-tile per thread
    int olr = mr * 4, oc0 = mc * 4;
    #pragma unroll 1
    for (int g = 0; g < PPB; ++g) {
        int plane = pb + g;
        float w[9];                        // sc1 loads; same addr per wave
        #pragma unroll
        for (int i = 0; i < 9; ++i) w[i] = ALD(&w9[plane * 9 + i]);
        float rowv[6][6];                  // lds rows olr..olr+5
        #pragma unroll
        for (int j = 0; j < 6; ++j) {
            const float* rp = &plane_lds[(olr + j) * 132 + oc0];
            float4 a  = *(const float4*)rp;       // 16B-aligned b128
            float2 c2 = *(const float2*)(rp + 4); // 8B-aligned b64
            rowv[j][0] = a.x; rowv[j][1] = a.y; rowv[j][2] = a.z; rowv[j][3] = a.w;
            rowv[j][4] = c2.x; rowv[j][5] = c2.y;
        }
        float* po = out + (size_t)plane * HW_;
        #pragma unroll
        for (int rr = 0; rr < 4; ++rr) {
            float res[4];
            #pragma unroll
            for (int cc = 0; cc < 4; ++cc) {
                float s = 0.f;
                #pragma unroll
                for (int dy = 0; dy < 3; ++dy)
                    #pragma unroll
                    for (int dx = 0; dx < 3; ++dx)
                        s += w[dy * 3 + dx] * rowv[rr + dy][cc + dx];
                res[cc] = s;
            }
            nfloat4 rv = { res[0], res[1], res[2], res[3] };
            __builtin_nontemporal_store(rv,
                (nfloat4*)&po[(olr + rr) * W_ + oc0]);
        }
        if (g < PPB - 1) {
            __syncthreads();               // rowv reads of plane g done
            #pragma unroll
            for (int i = 0; i < 5; ++i) {  // write pre (plane g+1) -> LDS
                int vi = i * 1024 + t;
                if (vi < 4160) {
                    int lr = vi >> 5, c4 = (vi & 31) << 2;
                    float* d = &plane_lds[lr * 132 + c4 + 1];
                    d[0] = pre[i].x; d[1] = pre[i].y;
                    d[2] = pre[i].z; d[3] = pre[i].w;
                }
            }
            __syncthreads();
            if (g < PPB - 2) {             // issue plane g+2 loads early
                const float* xn = x + (size_t)(plane + 2) * HW_;
                #pragma unroll
                for (int i = 0; i < 5; ++i) {
                    int vi = i * 1024 + t;
                    if (vi < 4160) {
                        int lr = vi >> 5, c4 = (vi & 31) << 2, gr = lr - 1;
                        pre[i] = (gr >= 0 && gr < H_)
                               ? *(const float4*)&xn[gr * W_ + c4]
                               : make_float4(0.f, 0.f, 0.f, 0.f);
                    }
                }
            }
        }
    }
}

extern "C" void kernel_launch(void* const* d_in, const int* in_sizes, int n_in,
                              void* d_out, int out_size, void* d_ws, size_t ws_size,
                              hipStream_t stream) {
    const float* x     = (const float*)d_in[0];
    const float* wconv = (const float*)d_in[1];
    const float* gamma = (const float*)d_in[2];
    const float* beta  = (const float*)d_in[3];
    float* out = (float*)d_out;

    float* xpT = (float*)d_ws;                   // C*N*256 = 262144 floats
    float* w9  = xpT + C_ * N_ * 256;            // N*256*OC = 9216 floats
    unsigned* bar = (unsigned*)(w9 + N_ * 256 * OC);   // 2 counters

    hipMemsetAsync(bar, 0, 2 * sizeof(unsigned), stream);  // ws is poisoned
    hipLaunchKernelGGL(fused_kernel, dim3(NBLK), dim3(1024), 0, stream,
                       x, wconv, gamma, beta, xpT, w9, out, bar);
}